// Round 1
// baseline (455.526 us; speedup 1.0000x reference)
//
#include <hip/hip_runtime.h>
#include <cstdint>
#include <cstddef>

typedef unsigned short u16;
typedef __attribute__((ext_vector_type(8))) short short8;    // 8 bf16 (4 VGPRs) MFMA A/B frag
typedef __attribute__((ext_vector_type(4))) float float4v;   // MFMA C/D frag
typedef __attribute__((ext_vector_type(4))) unsigned short ushort4v;

// ---------- helpers ----------
__device__ __forceinline__ u16 f2bf(float f) {
    union { float f; uint32_t u; } x; x.f = f;
    uint32_t r = x.u + 0x7fffu + ((x.u >> 16) & 1u);   // RTNE
    return (u16)(r >> 16);
}
__device__ __forceinline__ float bf2f(u16 b) {
    union { uint32_t u; float f; } x; x.u = ((uint32_t)b) << 16;
    return x.f;
}
// async global->LDS, 16B per lane; LDS dest must be wave-uniform base (HW adds lane*16)
__device__ __forceinline__ void gload_lds16(const u16* g, u16* l) {
    __builtin_amdgcn_global_load_lds(
        (const __attribute__((address_space(1))) void*)g,
        (__attribute__((address_space(3))) void*)l,
        16, 0, 0);
}

// ---------- 1. cast x (fp32 -> bf16), 4 elems/thread ----------
__global__ __launch_bounds__(256) void cast_x(const float4v* __restrict__ x,
                                              ushort4v* __restrict__ xb, int n4) {
    int i = blockIdx.x * 256 + threadIdx.x;
    if (i >= n4) return;
    float4v v = x[i];
    ushort4v o;
    #pragma unroll
    for (int j = 0; j < 4; ++j) o[j] = f2bf(v[j]);
    xb[i] = o;
}

// ---------- 2. transpose+cast weights: dst[n*2048+k] = src[k*Ns+n] ----------
__global__ __launch_bounds__(256) void transpose_cast(const float* __restrict__ src,
                                                      u16* __restrict__ dst, int Ns) {
    __shared__ float lds[32][33];
    const int tid = threadIdx.x;
    const int n0 = blockIdx.x * 32;
    const int k0 = blockIdx.y * 32;
    const int row = tid >> 3;            // k local
    const int c4  = (tid & 7) * 4;       // n local
    const float4v v = *(const float4v*)(src + (size_t)(k0 + row) * Ns + n0 + c4);
    #pragma unroll
    for (int i = 0; i < 4; ++i) lds[row][c4 + i] = v[i];
    __syncthreads();
    const int nrow = tid >> 3;           // n local
    const int k4   = (tid & 7) * 4;      // k local
    ushort4v o;
    #pragma unroll
    for (int i = 0; i < 4; ++i) o[i] = f2bf(lds[k4 + i][nrow]);
    *(ushort4v*)(dst + (size_t)(n0 + nrow) * 2048 + k0 + k4) = o;
}

// ---------- 3. GEMM: C[M,N] = A[M,K] * Bt[N,K]^T   (bf16 in, bf16/fp32 out) ----------
// m97 structure: 128x128 tile, 4 waves each 64x64 (4x4 MFMA tiles), BK=32,
// global_load_lds width-16 staging, ds_read_b128 frags.
template<int WRITE_BF16>
__global__ __launch_bounds__(256) void gemm_bt(const u16* __restrict__ A,
                                               const u16* __restrict__ Bt,
                                               void* __restrict__ Cv,
                                               int M, int N, int K) {
    __shared__ u16 lds_a[128 * 32];
    __shared__ u16 lds_b[128 * 32];
    const int tid  = threadIdx.x;
    const int wave = tid >> 6;
    const int lane = tid & 63;
    const int quad = lane >> 4;
    const int l15  = lane & 15;
    const long m0 = (long)blockIdx.x * 128;
    const long n0 = (long)blockIdx.y * 128;
    const int wm = (wave >> 1) * 64;
    const int wn = (wave & 1) * 64;
    const int sa_row = lane >> 2;          // 0..15
    const int sa_col = (lane & 3) * 8;     // 0,8,16,24

    float4v acc[4][4];
    #pragma unroll
    for (int i = 0; i < 4; ++i)
        #pragma unroll
        for (int j = 0; j < 4; ++j)
            #pragma unroll
            for (int r = 0; r < 4; ++r) acc[i][j][r] = 0.0f;

    for (int k0 = 0; k0 < K; k0 += 32) {
        #pragma unroll
        for (int i = 0; i < 2; ++i) {
            const int slot = wave * 2 + i;          // 0..7, 16 rows each
            const u16* ga = A  + (m0 + slot * 16 + sa_row) * (long)K + k0 + sa_col;
            gload_lds16(ga, lds_a + slot * 512);
            const u16* gb = Bt + (n0 + slot * 16 + sa_row) * (long)K + k0 + sa_col;
            gload_lds16(gb, lds_b + slot * 512);
        }
        __syncthreads();
        short8 af[4], bfr[4];
        #pragma unroll
        for (int mt = 0; mt < 4; ++mt)
            af[mt] = *(const short8*)(lds_a + (wm + mt * 16 + l15) * 32 + quad * 8);
        #pragma unroll
        for (int nt = 0; nt < 4; ++nt)
            bfr[nt] = *(const short8*)(lds_b + (wn + nt * 16 + l15) * 32 + quad * 8);
        #pragma unroll
        for (int mt = 0; mt < 4; ++mt)
            #pragma unroll
            for (int nt = 0; nt < 4; ++nt)
                acc[mt][nt] = __builtin_amdgcn_mfma_f32_16x16x32_bf16(af[mt], bfr[nt], acc[mt][nt], 0, 0, 0);
        __syncthreads();
    }
    // epilogue: C/D layout row=quad*4+r, col=l15
    #pragma unroll
    for (int mt = 0; mt < 4; ++mt) {
        #pragma unroll
        for (int nt = 0; nt < 4; ++nt) {
            const long gr = m0 + wm + mt * 16 + quad * 4;
            const long gc = n0 + wn + nt * 16 + l15;
            #pragma unroll
            for (int r = 0; r < 4; ++r) {
                const float v = acc[mt][nt][r];
                if (WRITE_BF16) ((u16*)Cv)[(gr + r) * N + gc] = f2bf(v);
                else            ((float*)Cv)[(gr + r) * N + gc] = v;
            }
        }
    }
}

// ---------- 4. per-head RMSNorm + RoPE for Q,K (one wave per (token,head)) ----------
// Q gets softmax scale 1/8 folded in. Layouts: Qr[b][h][t][d], Kr[b][kh][t][d].
__global__ __launch_bounds__(256) void norm_rope(const u16* __restrict__ qkv,
                                                 const float* __restrict__ qw,
                                                 const float* __restrict__ kw,
                                                 u16* __restrict__ Qr, u16* __restrict__ Kr) {
    const int W = blockIdx.x * 4 + (threadIdx.x >> 6);   // warp id, < 163840
    const int lane = threadIdx.x & 63;                   // = d
    const int token = W / 40;
    const int u = W - token * 40;                        // 0..31 Q head, 32..39 K head
    const int b = token >> 11;
    const int t = token & 2047;
    const bool isQ = (u < 32);
    const int col = isQ ? (u * 64 + lane) : (2048 + (u - 32) * 64 + lane);
    const float v = bf2f(qkv[(size_t)token * 3072 + col]);
    float ss = v * v;
    #pragma unroll
    for (int m = 1; m < 64; m <<= 1) ss += __shfl_xor(ss, m);
    const float rms = rsqrtf(ss * (1.0f / 64.0f) + 1e-5f);
    const float w = isQ ? qw[lane] : kw[lane];
    const float vn = v * rms * w;
    const float partner = __shfl_xor(vn, 32);
    const int i = lane & 31;
    // inv_freq = 1e6^(-i/32) = 2^(-i*log2(1e6)/32)
    const float invf = exp2f(-(float)i * (19.931568569324174f / 32.0f));
    const float ang = (float)t * invf;
    float sv, cv;
    sincosf(ang, &sv, &cv);
    float outv = vn * cv + ((lane < 32) ? -partner : partner) * sv;
    if (isQ) {
        outv *= 0.125f;   // fold 1/sqrt(64)
        Qr[(((size_t)b * 32 + u) * 2048 + t) * 64 + lane] = f2bf(outv);
    } else {
        Kr[(((size_t)b * 8 + (u - 32)) * 2048 + t) * 64 + lane] = f2bf(outv);
    }
}

// ---------- 5. V transpose: Vr[b][kh][d][t] (so PV's V^T stages contiguously) ----------
__global__ __launch_bounds__(256) void v_transpose(const u16* __restrict__ qkv,
                                                   u16* __restrict__ Vr) {
    __shared__ u16 lds[32][36];
    const int tid = threadIdx.x;
    const int t0 = blockIdx.x * 32;
    const int d0 = blockIdx.y * 32;
    const int head = blockIdx.z;            // b*8+kh
    const int b = head >> 3, kh = head & 7;
    const int row = tid >> 3;               // t local
    const int c4  = (tid & 7) * 4;          // d local
    ushort4v val = *(const ushort4v*)(qkv + (size_t)(b * 2048 + t0 + row) * 3072
                                          + 2560 + kh * 64 + d0 + c4);
    #pragma unroll
    for (int i = 0; i < 4; ++i) lds[row][c4 + i] = val[i];
    __syncthreads();
    const int drow = tid >> 3;              // d local
    const int t4   = (tid & 7) * 4;         // t local
    ushort4v o;
    #pragma unroll
    for (int i = 0; i < 4; ++i) o[i] = lds[t4 + i][drow];
    *(ushort4v*)(Vr + ((size_t)head * 64 + d0 + drow) * 2048 + t0 + t4) = o;
}

// ---------- 6. flash attention (causal, GQA): Q-tile 64 rows, K-tile 128 ----------
#define KSTR 72    // lds_k row stride (d padded 64->72)
#define VSTR 136   // lds_vt row stride (key padded 128->136)
#define PSTR 136
__global__ __launch_bounds__(256) void attn_fwd(const u16* __restrict__ Qr,
                                                const u16* __restrict__ Kr,
                                                const u16* __restrict__ Vt,
                                                u16* __restrict__ Ob) {
    __shared__ u16 lds_k[128 * KSTR];
    __shared__ u16 lds_vt[64 * VSTR];
    __shared__ u16 lds_p[4 * 16 * PSTR];    // per-wave P (16x128) scratch
    const int tid  = threadIdx.x;
    const int wave = tid >> 6;
    const int lane = tid & 63;
    const int quad = lane >> 4;
    const int l15  = lane & 15;
    const int qt0 = blockIdx.x * 64;
    const int bh = blockIdx.y;              // 0..63
    const int b = bh >> 5, h = bh & 31;
    const int kh = h >> 2;
    const u16* Qh = Qr + ((size_t)(b * 32 + h))  * 2048 * 64;
    const u16* Kh = Kr + ((size_t)(b * 8 + kh))  * 2048 * 64;
    const u16* Vh = Vt + ((size_t)(b * 8 + kh))  * 64 * 2048;

    // Q A-frags in registers (wave owns rows [qt0+wave*16, +16))
    short8 qf[2];
    {
        const int qrow = qt0 + wave * 16 + l15;
        #pragma unroll
        for (int ks = 0; ks < 2; ++ks)
            qf[ks] = *(const short8*)(Qh + (size_t)qrow * 64 + ks * 32 + quad * 8);
    }
    float m_i[4], l_i[4];
    #pragma unroll
    for (int r = 0; r < 4; ++r) { m_i[r] = -1e30f; l_i[r] = 0.0f; }
    float4v Oacc[4];
    #pragma unroll
    for (int n = 0; n < 4; ++n)
        #pragma unroll
        for (int r = 0; r < 4; ++r) Oacc[n][r] = 0.0f;

    const int ktmax = qt0 >> 7;
    for (int kt = 0; kt <= ktmax; ++kt) {
        const int kt0 = kt << 7;
        // stage K tile 128x64 -> lds_k[key][d] (pad 72)
        #pragma unroll
        for (int j = 0; j < 4; ++j) {
            const int idx = j * 256 + tid;
            const int key = idx >> 3;
            const int d0  = (idx & 7) * 8;
            short8 v = *(const short8*)(Kh + (size_t)(kt0 + key) * 64 + d0);
            *(short8*)(lds_k + key * KSTR + d0) = v;
        }
        // stage V^T tile 64x128 -> lds_vt[d][key] (pad 136)
        #pragma unroll
        for (int j = 0; j < 4; ++j) {
            const int idx = j * 256 + tid;
            const int d  = idx >> 4;
            const int k8 = (idx & 15) * 8;
            short8 v = *(const short8*)(Vh + (size_t)d * 2048 + kt0 + k8);
            *(short8*)(lds_vt + d * VSTR + k8) = v;
        }
        __syncthreads();

        // S = Q*K^T (scale already folded into Q)
        float4v S[8];
        #pragma unroll
        for (int nt = 0; nt < 8; ++nt)
            #pragma unroll
            for (int r = 0; r < 4; ++r) S[nt][r] = 0.0f;
        #pragma unroll
        for (int ks = 0; ks < 2; ++ks)
            #pragma unroll
            for (int nt = 0; nt < 8; ++nt) {
                short8 kf = *(const short8*)(lds_k + (nt * 16 + l15) * KSTR + ks * 32 + quad * 8);
                S[nt] = __builtin_amdgcn_mfma_f32_16x16x32_bf16(qf[ks], kf, S[nt], 0, 0, 0);
            }
        // causal mask (only needed on tiles straddling the diagonal)
        if (kt0 + 127 > qt0) {
            #pragma unroll
            for (int nt = 0; nt < 8; ++nt) {
                const int gcol = kt0 + nt * 16 + l15;
                #pragma unroll
                for (int r = 0; r < 4; ++r) {
                    const int grow = qt0 + wave * 16 + quad * 4 + r;
                    if (gcol > grow) S[nt][r] = -1e30f;
                }
            }
        }
        // online softmax; stats per row (row = quad*4+r), reduce across l15 group
        float alpha[4];
        #pragma unroll
        for (int r = 0; r < 4; ++r) {
            float mx = S[0][r];
            #pragma unroll
            for (int nt = 1; nt < 8; ++nt) mx = fmaxf(mx, S[nt][r]);
            #pragma unroll
            for (int mm = 1; mm < 16; mm <<= 1) mx = fmaxf(mx, __shfl_xor(mx, mm));
            const float mnew = fmaxf(m_i[r], mx);
            alpha[r] = __expf(m_i[r] - mnew);
            m_i[r] = mnew;
            float rs = 0.0f;
            #pragma unroll
            for (int nt = 0; nt < 8; ++nt) {
                const float p = __expf(S[nt][r] - mnew);
                S[nt][r] = p;
                rs += p;
            }
            #pragma unroll
            for (int mm = 1; mm < 16; mm <<= 1) rs += __shfl_xor(rs, mm);
            l_i[r] = l_i[r] * alpha[r] + rs;
        }
        #pragma unroll
        for (int nd = 0; nd < 4; ++nd)
            #pragma unroll
            for (int r = 0; r < 4; ++r) Oacc[nd][r] *= alpha[r];

        // P: C/D layout -> LDS -> A-operand layout (wave-private; same-wave LDS is in-order)
        u16* pw = lds_p + wave * 16 * PSTR;
        #pragma unroll
        for (int nt = 0; nt < 8; ++nt)
            #pragma unroll
            for (int r = 0; r < 4; ++r)
                pw[(quad * 4 + r) * PSTR + nt * 16 + l15] = f2bf(S[nt][r]);
        // O += P*V
        #pragma unroll
        for (int ks = 0; ks < 4; ++ks) {
            short8 pf = *(const short8*)(pw + l15 * PSTR + ks * 32 + quad * 8);
            #pragma unroll
            for (int nd = 0; nd < 4; ++nd) {
                short8 vf = *(const short8*)(lds_vt + (nd * 16 + l15) * VSTR + ks * 32 + quad * 8);
                Oacc[nd] = __builtin_amdgcn_mfma_f32_16x16x32_bf16(pf, vf, Oacc[nd], 0, 0, 0);
            }
        }
        __syncthreads();
    }
    // epilogue: write attn out [token][h*64+d] bf16
    #pragma unroll
    for (int nd = 0; nd < 4; ++nd) {
        const int gcol = h * 64 + nd * 16 + l15;
        #pragma unroll
        for (int r = 0; r < 4; ++r) {
            const int grow = qt0 + wave * 16 + quad * 4 + r;
            const float v = Oacc[nd][r] / l_i[r];
            Ob[((size_t)(b * 2048 + grow)) * 2048 + gcol] = f2bf(v);
        }
    }
}

// ---------- launcher ----------
extern "C" void kernel_launch(void* const* d_in, const int* in_sizes, int n_in,
                              void* d_out, int out_size, void* d_ws, size_t ws_size,
                              hipStream_t stream) {
    (void)in_sizes; (void)n_in; (void)out_size; (void)ws_size;
    const float* x  = (const float*)d_in[0];
    const float* Wq = (const float*)d_in[1];
    const float* Wk = (const float*)d_in[2];
    const float* Wv = (const float*)d_in[3];
    const float* Wo = (const float*)d_in[4];
    const float* qw = (const float*)d_in[5];
    const float* kw = (const float*)d_in[6];
    float* out = (float*)d_out;

    char* ws = (char*)d_ws;
    size_t off = 0;
    auto alloc = [&](size_t bytes) {
        char* p = ws + off;
        off += (bytes + 255) & ~(size_t)255;
        return p;
    };
    u16* xb     = (u16*)alloc((size_t)8388608 * 2);        // x bf16          16 MB
    u16* wqkv_t = (u16*)alloc((size_t)3072 * 2048 * 2);    // [n][k]          12 MB
    u16* wo_t   = (u16*)alloc((size_t)2048 * 2048 * 2);    //                  8 MB
    u16* qkv    = (u16*)alloc((size_t)4096 * 3072 * 2);    // gemm1 out       24 MB
    u16* q_r    = (u16*)alloc((size_t)2 * 32 * 2048 * 64 * 2);  // 16 MB
    u16* k_r    = (u16*)alloc((size_t)2 * 8 * 2048 * 64 * 2);   //  4 MB
    u16* v_r    = (u16*)alloc((size_t)2 * 8 * 64 * 2048 * 2);   //  4 MB (d-major)
    u16* attnb  = xb;   // reuse: xb dead after gemm1

    hipLaunchKernelGGL(cast_x, dim3(8192), dim3(256), 0, stream,
                       (const float4v*)x, (ushort4v*)xb, 2097152);
    hipLaunchKernelGGL(transpose_cast, dim3(64, 64), dim3(256), 0, stream, Wq, wqkv_t, 2048);
    hipLaunchKernelGGL(transpose_cast, dim3(16, 64), dim3(256), 0, stream, Wk, wqkv_t + (size_t)2048 * 2048, 512);
    hipLaunchKernelGGL(transpose_cast, dim3(16, 64), dim3(256), 0, stream, Wv, wqkv_t + (size_t)2560 * 2048, 512);
    hipLaunchKernelGGL(transpose_cast, dim3(64, 64), dim3(256), 0, stream, Wo, wo_t, 2048);
    hipLaunchKernelGGL(HIP_KERNEL_NAME(gemm_bt<1>), dim3(32, 24), dim3(256), 0, stream,
                       xb, wqkv_t, (void*)qkv, 4096, 3072, 2048);
    hipLaunchKernelGGL(norm_rope, dim3(40960), dim3(256), 0, stream, qkv, qw, kw, q_r, k_r);
    hipLaunchKernelGGL(v_transpose, dim3(64, 2, 16), dim3(256), 0, stream, qkv, v_r);
    hipLaunchKernelGGL(attn_fwd, dim3(32, 64), dim3(256), 0, stream, q_r, k_r, v_r, attnb);
    hipLaunchKernelGGL(HIP_KERNEL_NAME(gemm_bt<0>), dim3(32, 16), dim3(256), 0, stream,
                       attnb, wo_t, (void*)out, 4096, 2048, 2048);
}